// Round 18
// baseline (80.556 us; speedup 1.0000x reference)
//
#include <hip/hip_runtime.h>

#define B_   4
#define L_   1024
#define D_   16
#define H_   32
#define TAU_ 64
#define EMB_ 8
#define AEP_ 34   // ae_lds stride: even -> 8B-aligned f2 reads, 2-way banks (free)
#define TI_  16   // i-tile height (4 rows/wave)
#define JT_  128  // j-tile width: two 64-wide subtiles per wave -> grid 2048

typedef float f2 __attribute__((ext_vector_type(2)));

// ---------------------------------------------------------------------------
// Kernel 1: precompute (R9 verbatim)
//   ai[b,l,h] = x[b,l,:] @ W1[0:16, h]
//   aj[b,l,h] = x[b,l,:] @ W1[16:32, h]
//   ae[t,h]   = dt_table[t,:] @ W1[32:40, h] + b1[h]
// ---------------------------------------------------------------------------
__global__ __launch_bounds__(256) void precompute_kernel(
    const float* __restrict__ x, const float* __restrict__ dtt,
    const float* __restrict__ W1, const float* __restrict__ b1,
    float* __restrict__ ai, float* __restrict__ aj, float* __restrict__ ae)
{
    const int id = blockIdx.x * 256 + threadIdx.x;
    const int NA = B_ * L_ * H_;
    if (id < NA) {
        const int h   = id & (H_ - 1);
        const int row = id >> 5;                 // b*L + l
        const float4* xr4 = (const float4*)(x + row * D_);
        const float4 v0 = xr4[0], v1 = xr4[1], v2 = xr4[2], v3 = xr4[3];
        const float xv[D_] = {v0.x, v0.y, v0.z, v0.w, v1.x, v1.y, v1.z, v1.w,
                              v2.x, v2.y, v2.z, v2.w, v3.x, v3.y, v3.z, v3.w};
        float s1 = 0.f, s2 = 0.f;
#pragma unroll
        for (int d = 0; d < D_; ++d) {
            s1 = fmaf(xv[d], W1[d * H_ + h], s1);
            s2 = fmaf(xv[d], W1[(D_ + d) * H_ + h], s2);
        }
        ai[id] = s1;
        aj[id] = s2;
    } else {
        const int k = id - NA;
        if (k < (TAU_ + 1) * H_) {
            const int h = k & (H_ - 1);
            const int t = k >> 5;
            float s = b1[h];
#pragma unroll
            for (int e = 0; e < EMB_; ++e)
                s = fmaf(dtt[t * EMB_ + e], W1[(2 * D_ + e) * H_ + h], s);
            ae[k] = s;
        }
    }
}

// ---------------------------------------------------------------------------
// Kernel 2: bias kernel, clean j-amortization (R14 retry without confounds).
// R16/R17 model: body ~= LDS-pipe(10us) + VALU(7.8us), dependency-chained.
// Halve the LDS term: tile 16i x 128j (grid stays 2048 = 8 blocks/CU), each
// wave = 4 rows x 2 j-subtiles (ja, ja+64); one broadcast row read feeds 128
// outputs; staging halves too (16 rows). launch_bounds(256,6): VGPR cap ~84
// fits r2a+r2b (~64) without spills; 24 waves/CU (75% occ ~ free per R9).
// All else R13-proven: NT dword stores, coalesced float4 aj, band ae_lds.
// ---------------------------------------------------------------------------
__global__ __launch_bounds__(256, 6) void bias_kernel(
    const float* __restrict__ ai, const float* __restrict__ aj,
    const float* __restrict__ ae, const float* __restrict__ W2,
    const float* __restrict__ b2p, float* __restrict__ out)
{
    __shared__ float ai_lds[TI_ * H_];            // 2 KB: this block's ai tile
    __shared__ float ae_lds[(TAU_ + 1) * AEP_];   // 8.84 KB: band blocks only

    const int b    = blockIdx.z;
    const int i0   = blockIdx.y * TI_;
    const int j0   = blockIdx.x * JT_;
    const int tid  = threadIdx.x;
    const int lane = tid & 63;
    const int w    = __builtin_amdgcn_readfirstlane(tid >> 6);
    const int ja   = j0 + lane;          // subtile A column; subtile B = ja+64

    const bool c0  = (j0 >= i0 + TI_);            // dt==0 over whole tile
    const bool c64 = (i0 >= j0 + JT_ + TAU_);     // dt==64 over whole tile
    const bool constpath = c0 || c64;

    const float b2 = *b2p;

    // ---- Stage ai tile: 16 rows x 32 h = 128 float4 (threads 0-127). ----
    if (tid < TI_ * H_ / 4) {
        const float4* src = (const float4*)(ai + ((size_t)(b * L_ + i0)) * H_);
        ((float4*)ai_lds)[tid] = src[tid];
    }

    // Per-lane column vectors for the two owned j's (R13 pattern x2).
    f2 r2a[H_ / 2], r2b[H_ / 2];
    {
        const float* ajrA = aj + ((size_t)(b * L_ + ja)) * H_;
        const float* ajrB = ajrA + 64 * H_;
#pragma unroll
        for (int h = 0; h < H_; h += 4) {
            const float4 va = *(const float4*)(ajrA + h);
            const float4 vb = *(const float4*)(ajrB + h);
            r2a[(h >> 1) + 0] = (f2){va.x, va.y};
            r2a[(h >> 1) + 1] = (f2){va.z, va.w};
            r2b[(h >> 1) + 0] = (f2){vb.x, vb.y};
            r2b[(h >> 1) + 1] = (f2){vb.z, vb.w};
        }
    }

    if (constpath) {
        const float* aec = ae + (c0 ? 0 : TAU_) * H_;   // uniform -> s_load once
#pragma unroll
        for (int h = 0; h < H_; h += 2) {
            const f2 e = {aec[h], aec[h + 1]};
            r2a[h >> 1] += e;
            r2b[h >> 1] += e;
        }
    } else {
        for (int k = tid; k < (TAU_ + 1) * H_; k += 256)
            ae_lds[(k >> 5) * AEP_ + (k & 31)] = ae[k];
    }
    __syncthreads();   // covers ai_lds (all paths) + ae_lds (band)

    const float* aiW = &ai_lds[(w * 4) * H_];   // wave's 4 rows in LDS
    float* outb = out + ((size_t)b) * L_ * L_ + ((size_t)(i0 + w * 4)) * L_ + ja;
    const f2 z2 = {0.f, 0.f};

    if (constpath) {
        const float pc = b2 - 0.2f * (c0 ? 0.f : (float)TAU_);
#pragma unroll
        for (int ii = 0; ii < 4; ++ii) {
            const float4* ar = (const float4*)&aiW[ii * H_];   // uniform bcast
            f2 accA = z2, accB = z2;
#pragma unroll
            for (int q = 0; q < 8; ++q) {
                const float4 qa = ar[q];        // one read feeds both subtiles
                const int h = q * 4;
                const f2 wv0 = {W2[h], W2[h + 1]};
                const f2 wv1 = {W2[h + 2], W2[h + 3]};
                const f2 a0 = {qa.x, qa.y};
                const f2 a1 = {qa.z, qa.w};
                f2 pA0 = a0 + r2a[(h >> 1) + 0];
                f2 pA1 = a1 + r2a[(h >> 1) + 1];
                f2 pB0 = a0 + r2b[(h >> 1) + 0];
                f2 pB1 = a1 + r2b[(h >> 1) + 1];
                pA0 = __builtin_elementwise_max(pA0, z2);
                pA1 = __builtin_elementwise_max(pA1, z2);
                pB0 = __builtin_elementwise_max(pB0, z2);
                pB1 = __builtin_elementwise_max(pB1, z2);
                accA = __builtin_elementwise_fma(pA0, wv0, accA);
                accA = __builtin_elementwise_fma(pA1, wv1, accA);
                accB = __builtin_elementwise_fma(pB0, wv0, accB);
                accB = __builtin_elementwise_fma(pB1, wv1, accB);
            }
            float* o = outb + (size_t)ii * L_;
            __builtin_nontemporal_store(accA.x + accA.y + pc, o);
            __builtin_nontemporal_store(accB.x + accB.y + pc, o + 64);
        }
    } else {
#pragma unroll
        for (int ii = 0; ii < 4; ++ii) {
            const int i   = i0 + w * 4 + ii;
            const int dA  = i - ja;
            const int dB  = dA - 64;
            const int dtA = dA < 0 ? 0 : (dA > TAU_ ? TAU_ : dA);
            const int dtB = dB < 0 ? 0 : (dB > TAU_ ? TAU_ : dB);
            const f2* eA  = (const f2*)&ae_lds[dtA * AEP_];   // 8B aligned
            const f2* eB  = (const f2*)&ae_lds[dtB * AEP_];
            const float4* ar = (const float4*)&aiW[ii * H_];
            f2 accA = z2, accB = z2;
#pragma unroll
            for (int q = 0; q < 8; ++q) {
                const float4 qa = ar[q];
                const int h = q * 4;
                const f2 wv0 = {W2[h], W2[h + 1]};
                const f2 wv1 = {W2[h + 2], W2[h + 3]};
                const f2 a0 = {qa.x, qa.y};
                const f2 a1 = {qa.z, qa.w};
                f2 pA0 = a0 + r2a[(h >> 1) + 0] + eA[(h >> 1) + 0];
                f2 pA1 = a1 + r2a[(h >> 1) + 1] + eA[(h >> 1) + 1];
                f2 pB0 = a0 + r2b[(h >> 1) + 0] + eB[(h >> 1) + 0];
                f2 pB1 = a1 + r2b[(h >> 1) + 1] + eB[(h >> 1) + 1];
                pA0 = __builtin_elementwise_max(pA0, z2);
                pA1 = __builtin_elementwise_max(pA1, z2);
                pB0 = __builtin_elementwise_max(pB0, z2);
                pB1 = __builtin_elementwise_max(pB1, z2);
                accA = __builtin_elementwise_fma(pA0, wv0, accA);
                accA = __builtin_elementwise_fma(pA1, wv1, accA);
                accB = __builtin_elementwise_fma(pB0, wv0, accB);
                accB = __builtin_elementwise_fma(pB1, wv1, accB);
            }
            float* o = outb + (size_t)ii * L_;
            __builtin_nontemporal_store(accA.x + accA.y + b2 - 0.2f * (float)dtA, o);
            __builtin_nontemporal_store(accB.x + accB.y + b2 - 0.2f * (float)dtB, o + 64);
        }
    }
}

extern "C" void kernel_launch(void* const* d_in, const int* in_sizes, int n_in,
                              void* d_out, int out_size, void* d_ws, size_t ws_size,
                              hipStream_t stream) {
    const float* x   = (const float*)d_in[0];
    const float* dtt = (const float*)d_in[1];
    const float* W1  = (const float*)d_in[2];
    const float* b1  = (const float*)d_in[3];
    const float* W2  = (const float*)d_in[4];
    const float* b2  = (const float*)d_in[5];
    float* out = (float*)d_out;

    float* ws = (float*)d_ws;
    float* ai = ws;                          // B*L*H floats
    float* aj = ws + B_ * L_ * H_;           // B*L*H floats
    float* ae = ws + 2 * B_ * L_ * H_;       // 65*H floats

    const int total  = B_ * L_ * H_ + (TAU_ + 1) * H_;
    const int blocks = (total + 255) / 256;
    hipLaunchKernelGGL(precompute_kernel, dim3(blocks), dim3(256), 0, stream,
                       x, dtt, W1, b1, ai, aj, ae);

    dim3 grid(L_ / JT_, L_ / TI_, B_);
    hipLaunchKernelGGL(bias_kernel, grid, dim3(256), 0, stream,
                       ai, aj, ae, W2, b2, out);
}

// Round 19
// 21.146 us; speedup vs baseline: 3.8095x; 3.8095x over previous
//
#include <hip/hip_runtime.h>

#define B_    4
#define L_    1024
#define D_    16
#define H_    32
#define TAU_  64
#define EMB_  8
#define AEPH_ 34   // ae_ldsh stride in halves: 17-word row stride -> conflict-free-ish
#define TI_   32   // i-tile height: 2048 blocks = 8 blocks/CU

typedef _Float16 h2 __attribute__((ext_vector_type(2)));
typedef float    f4 __attribute__((ext_vector_type(4)));

union V16 { f4 f; h2 h[4]; };   // 16B raw <-> 4x h2

#if defined(__has_builtin)
#  if __has_builtin(__builtin_amdgcn_fdot2)
#    define FDOT2(a, b, c) __builtin_amdgcn_fdot2((a), (b), (c), false)
#  endif
#endif
#ifndef FDOT2
#  define FDOT2(a, b, c) fmaf((float)(a)[1], (float)(b)[1], \
                          fmaf((float)(a)[0], (float)(b)[0], (c)))
#endif

// ---------------------------------------------------------------------------
// Kernel 1: precompute -> fp16 outputs.
//   aih/ajh[b,l,h] = x @ W1 halves; aeh[t,h] = emb @ W1c + b1; w2h = (f16)W2.
// ---------------------------------------------------------------------------
__global__ __launch_bounds__(256) void precompute_kernel(
    const float* __restrict__ x, const float* __restrict__ dtt,
    const float* __restrict__ W1, const float* __restrict__ b1,
    const float* __restrict__ W2,
    _Float16* __restrict__ aih, _Float16* __restrict__ ajh,
    _Float16* __restrict__ aeh, _Float16* __restrict__ w2h)
{
    const int id = blockIdx.x * 256 + threadIdx.x;
    const int NA = B_ * L_ * H_;
    if (id < NA) {
        const int h   = id & (H_ - 1);
        const int row = id >> 5;                 // b*L + l
        const float4* xr4 = (const float4*)(x + row * D_);
        const float4 v0 = xr4[0], v1 = xr4[1], v2 = xr4[2], v3 = xr4[3];
        const float xv[D_] = {v0.x, v0.y, v0.z, v0.w, v1.x, v1.y, v1.z, v1.w,
                              v2.x, v2.y, v2.z, v2.w, v3.x, v3.y, v3.z, v3.w};
        float s1 = 0.f, s2 = 0.f;
#pragma unroll
        for (int d = 0; d < D_; ++d) {
            s1 = fmaf(xv[d], W1[d * H_ + h], s1);
            s2 = fmaf(xv[d], W1[(D_ + d) * H_ + h], s2);
        }
        aih[id] = (_Float16)s1;
        ajh[id] = (_Float16)s2;
    } else {
        const int k = id - NA;
        if (k < (TAU_ + 1) * H_) {
            const int h = k & (H_ - 1);
            const int t = k >> 5;
            float s = b1[h];
#pragma unroll
            for (int e = 0; e < EMB_; ++e)
                s = fmaf(dtt[t * EMB_ + e], W1[(2 * D_ + e) * H_ + h], s);
            aeh[k] = (_Float16)s;
        } else if (k < (TAU_ + 1) * H_ + H_) {
            const int h = k - (TAU_ + 1) * H_;
            w2h[h] = (_Float16)W2[h];
        }
    }
}

// ---------------------------------------------------------------------------
// Kernel 2: bias kernel, fp16-packed edition (R13 shape, half the work).
// R16 profile: body 16.7us = VALU(39% busy, 96 ops/out) + LDS row reads,
// dependency-chained. This kernel halves BOTH: f16 data -> 4 ds_read_b128
// per row (was 8), and pk_add_f16 + pk_max_f16 + v_dot2_f32_f16 -> 1.5
// inst/h (was 3), f32 accumulation (no f16 accumulate error).
// Store/addressing shape is R13-verbatim (lane=j, one contiguous 256B NT
// dword store per wave-row) -- R12/R18 proved any other shape explodes HBM.
// ---------------------------------------------------------------------------
__global__ __launch_bounds__(256, 8) void bias_kernel(
    const _Float16* __restrict__ aih, const _Float16* __restrict__ ajh,
    const _Float16* __restrict__ aeh, const _Float16* __restrict__ w2h,
    const float* __restrict__ b2p, float* __restrict__ out)
{
    __shared__ _Float16 ai_ldsh[TI_ * H_];            // 2 KB
    __shared__ _Float16 ae_ldsh[(TAU_ + 1) * AEPH_];  // 4.4 KB (band only)

    const int b    = blockIdx.z;
    const int i0   = blockIdx.y * TI_;
    const int j0   = blockIdx.x * 64;
    const int tid  = threadIdx.x;
    const int lane = tid & 63;
    const int w    = __builtin_amdgcn_readfirstlane(tid >> 6);
    const int j    = j0 + lane;

    const bool c0  = (j0 >= i0 + TI_);     // dt==0 over whole tile
    const bool c64 = (i0 >= j0 + 128);     // dt==64 over whole tile
    const bool constpath = c0 || c64;

    const float b2 = *b2p;

    // ---- Stage ai tile: 32 rows x 32 halves = 2 KB = 256 x 8B. ----
    {
        const float2* src = (const float2*)(aih + ((size_t)(b * L_ + i0)) * H_);
        ((float2*)ai_ldsh)[tid] = src[tid];
    }

    // Per-lane column vector r2[16] (h2) = aj row (+ ae row on const path).
    h2 r2[16];
    {
        const f4* ajr = (const f4*)(ajh + ((size_t)(b * L_ + j)) * H_);
#pragma unroll
        for (int q = 0; q < 4; ++q) {
            V16 u; u.f = ajr[q];
            r2[q * 4 + 0] = u.h[0]; r2[q * 4 + 1] = u.h[1];
            r2[q * 4 + 2] = u.h[2]; r2[q * 4 + 3] = u.h[3];
        }
    }

    if (constpath) {
        const h2* aec = (const h2*)(aeh + (c0 ? 0 : TAU_) * H_);   // uniform
#pragma unroll
        for (int q = 0; q < 16; ++q) r2[q] += aec[q];
    } else {
        for (int k = tid; k < (TAU_ + 1) * H_; k += 256)
            ae_ldsh[(k >> 5) * AEPH_ + (k & 31)] = aeh[k];
    }
    __syncthreads();   // covers ai_ldsh (all paths) + ae_ldsh (band)

    // W2 in h2 pairs (uniform -> scalar regs).
    h2 w2r[16];
    {
        const h2* wsrc = (const h2*)w2h;
#pragma unroll
        for (int q = 0; q < 16; ++q) w2r[q] = wsrc[q];
    }

    const _Float16* aiW = &ai_ldsh[(w * 8) * H_];   // wave's 8 rows
    float* outb = out + ((size_t)b) * L_ * L_ + ((size_t)(i0 + w * 8)) * L_ + j;
    const h2 zh = {(_Float16)0.f, (_Float16)0.f};

    if (constpath) {
        const float pc = b2 - 0.2f * (c0 ? 0.f : (float)TAU_);
        for (int ii = 0; ii < 8; ii += 2) {
            const f4* ar0 = (const f4*)&aiW[(ii + 0) * H_];  // 4 x ds_read_b128
            const f4* ar1 = (const f4*)&aiW[(ii + 1) * H_];
            float a0a = 0.f, a0b = 0.f, a1a = 0.f, a1b = 0.f;
#pragma unroll
            for (int q = 0; q < 4; ++q) {
                V16 u0; u0.f = ar0[q];
                V16 u1; u1.f = ar1[q];
#pragma unroll
                for (int k = 0; k < 4; ++k) {
                    const int m = q * 4 + k;
                    h2 t0 = u0.h[k] + r2[m];            // v_pk_add_f16
                    h2 t1 = u1.h[k] + r2[m];
                    t0 = __builtin_elementwise_max(t0, zh);   // v_pk_max_f16
                    t1 = __builtin_elementwise_max(t1, zh);
                    if (k & 1) { a0b = FDOT2(t0, w2r[m], a0b);
                                 a1b = FDOT2(t1, w2r[m], a1b); }
                    else       { a0a = FDOT2(t0, w2r[m], a0a);
                                 a1a = FDOT2(t1, w2r[m], a1a); }
                }
            }
            __builtin_nontemporal_store(a0a + a0b + pc, outb + (size_t)(ii + 0) * L_);
            __builtin_nontemporal_store(a1a + a1b + pc, outb + (size_t)(ii + 1) * L_);
        }
    } else {
        for (int ii = 0; ii < 8; ++ii) {
            const int i   = i0 + w * 8 + ii;
            const int d   = i - j;
            const int dt  = d < 0 ? 0 : (d > TAU_ ? TAU_ : d);
            const h2* eL  = (const h2*)&ae_ldsh[dt * AEPH_];  // 4B aligned
            const f4* ar  = (const f4*)&aiW[ii * H_];
            float aa = 0.f, ab = 0.f;
#pragma unroll
            for (int q = 0; q < 4; ++q) {
                V16 u; u.f = ar[q];
#pragma unroll
                for (int k = 0; k < 4; ++k) {
                    const int m = q * 4 + k;
                    h2 t = u.h[k] + r2[m] + eL[m];
                    t = __builtin_elementwise_max(t, zh);
                    if (k & 1) ab = FDOT2(t, w2r[m], ab);
                    else       aa = FDOT2(t, w2r[m], aa);
                }
            }
            __builtin_nontemporal_store(aa + ab + b2 - 0.2f * (float)dt,
                                        outb + (size_t)ii * L_);
        }
    }
}

extern "C" void kernel_launch(void* const* d_in, const int* in_sizes, int n_in,
                              void* d_out, int out_size, void* d_ws, size_t ws_size,
                              hipStream_t stream) {
    const float* x   = (const float*)d_in[0];
    const float* dtt = (const float*)d_in[1];
    const float* W1  = (const float*)d_in[2];
    const float* b1  = (const float*)d_in[3];
    const float* W2  = (const float*)d_in[4];
    const float* b2  = (const float*)d_in[5];
    float* out = (float*)d_out;

    _Float16* wsh = (_Float16*)d_ws;
    _Float16* aih = wsh;                               // B*L*H halves
    _Float16* ajh = wsh + B_ * L_ * H_;                // B*L*H halves
    _Float16* aeh = wsh + 2 * B_ * L_ * H_;            // 65*H halves
    _Float16* w2h = aeh + (TAU_ + 1) * H_;             // H halves

    const int total  = B_ * L_ * H_ + (TAU_ + 1) * H_ + H_;
    const int blocks = (total + 255) / 256;
    hipLaunchKernelGGL(precompute_kernel, dim3(blocks), dim3(256), 0, stream,
                       x, dtt, W1, b1, W2, aih, ajh, aeh, w2h);

    dim3 grid(L_ / 64, L_ / TI_, B_);
    hipLaunchKernelGGL(bias_kernel, grid, dim3(256), 0, stream,
                       aih, ajh, aeh, w2h, b2, out);
}